// Round 7
// baseline (164.223 us; speedup 1.0000x reference)
//
#include <hip/hip_runtime.h>
#include <hip/hip_bf16.h>

#define CC 256
#define DD 64
#define PP 18
#define ROWS 32768
#define EPSF 1e-5f

typedef __attribute__((ext_vector_type(8))) short bf16x8;
typedef __attribute__((ext_vector_type(4))) short s16x4;
typedef __attribute__((ext_vector_type(4))) float f32x4;

// Relaxed barrier: make LDS writes visible across the workgroup WITHOUT
// draining outstanding global loads (vmcnt). __syncthreads() would emit
// s_waitcnt vmcnt(0) lgkmcnt(0) and kill the B-fragment pipeline.
#define BAR_LDS() do {                                        \
    asm volatile("s_waitcnt lgkmcnt(0)" ::: "memory");        \
    __builtin_amdgcn_s_barrier();                             \
    __builtin_amdgcn_sched_barrier(0);                        \
} while (0)

// ---------------------------------------------------------------------------
// One fused pack kernel: fp32 W[K][N] (k-major) -> MFMA B-fragment order bf16:
// out[((nt*(K/32) + ks)*64 + l)*8 + e] = W[ks*32 + (l>>4)*8 + e][nt*16 + (l&15)]
__global__ __launch_bounds__(256) void k_pack_all(
    const float* __restrict__ Wq, const float* __restrict__ Wk,
    const float* __restrict__ Wv, const float* __restrict__ Wo,
    const float* __restrict__ W1, const float* __restrict__ W2,
    __hip_bfloat16* __restrict__ WqP, __hip_bfloat16* __restrict__ WkP,
    __hip_bfloat16* __restrict__ WvP, __hip_bfloat16* __restrict__ WoP,
    __hip_bfloat16* __restrict__ W1P, __hip_bfloat16* __restrict__ W2P) {
    int i = blockIdx.x * 256 + threadIdx.x;
    const float* src; __hip_bfloat16* dst; int K, N, j;
    if (i < 16384)       { src = Wq; dst = WqP; K = 256;  N = 64;   j = i; }
    else if (i < 32768)  { src = Wk; dst = WkP; K = 256;  N = 64;   j = i - 16384; }
    else if (i < 49152)  { src = Wv; dst = WvP; K = 256;  N = 64;   j = i - 32768; }
    else if (i < 65536)  { src = Wo; dst = WoP; K = 64;   N = 256;  j = i - 49152; }
    else if (i < 327680) { src = W1; dst = W1P; K = 256;  N = 1024; j = i - 65536; }
    else if (i < 589824) { src = W2; dst = W2P; K = 1024; N = 256;  j = i - 327680; }
    else return;
    int e = j & 7, l = (j >> 3) & 63, rest = j >> 9;
    int KS = K >> 5;
    int ks = rest % KS, nt = rest / KS;
    int row = ks * 32 + (l >> 4) * 8 + e;
    int col = nt * 16 + (l & 15);
    dst[j] = __float2bfloat16(src[(long)row * N + col]);
}

// ---------------------------------------------------------------------------
// Fused QKV. 32 rows/block, 4 waves. A-frags hoisted; wave w computes
// n-tiles {3w..3w+2} of 12 (Q:0-3,K:4-7,V:8-11).
__global__ __launch_bounds__(256) void k_qkv(
    const float4* __restrict__ X4, const float4* __restrict__ pe4,
    const __hip_bfloat16* __restrict__ WqP, const __hip_bfloat16* __restrict__ WkP,
    const __hip_bfloat16* __restrict__ WvP,
    const float* __restrict__ bq, const float* __restrict__ bk,
    const float* __restrict__ bv,
    __hip_bfloat16* __restrict__ Xpb,
    __hip_bfloat16* __restrict__ Qb, __hip_bfloat16* __restrict__ Kb,
    __hip_bfloat16* __restrict__ Vb) {
    __shared__ short Xs[32 * 256];      // 16 KB, swizzled
    const int t = threadIdx.x, w = t >> 6, l = t & 63;
    const int l15 = l & 15, lh = l >> 4;
    const int row0 = blockIdx.x * 32;

    for (int j = t; j < 2048; j += 256) {          // 32 rows x 64 float4
        int r = j >> 6, c4 = j & 63;
        long g = row0 + r;
        float4 a = X4[(g << 6) + c4];
        float4 p = pe4[(long)((g & 16383) << 6) + c4];
        union { s16x4 v; __hip_bfloat16 h[4]; } u;
        u.h[0] = __float2bfloat16(a.x + p.x);
        u.h[1] = __float2bfloat16(a.y + p.y);
        u.h[2] = __float2bfloat16(a.z + p.z);
        u.h[3] = __float2bfloat16(a.w + p.w);
        int db = (r << 9) + (c4 << 3);
        db ^= (r & 7) << 4;
        *(s16x4*)((char*)Xs + db) = u.v;
        *(s16x4*)((char*)Xpb + (g << 9) + (c4 << 3)) = u.v;
    }
    __syncthreads();

    // hoist A fragments: [ri][ks]
    bf16x8 af[2][8];
#pragma unroll
    for (int ri = 0; ri < 2; ++ri)
#pragma unroll
        for (int ks = 0; ks < 8; ++ks) {
            int r = ri * 16 + l15;
            int db = (r << 9) + ks * 64 + lh * 16;
            db ^= (r & 7) << 4;
            af[ri][ks] = *(const bf16x8*)((const char*)Xs + db);
        }

    f32x4 acc[3][2];
#pragma unroll
    for (int j = 0; j < 3; ++j)
#pragma unroll
        for (int ri = 0; ri < 2; ++ri) acc[j][ri] = (f32x4)(0.f);

    __builtin_amdgcn_s_setprio(1);
#pragma unroll
    for (int ks = 0; ks < 8; ++ks)
#pragma unroll
        for (int j = 0; j < 3; ++j) {
            int nt = w * 3 + j;
            const __hip_bfloat16* WP = (nt < 4) ? WqP : ((nt < 8) ? WkP : WvP);
            int ntl = nt & 3;
            bf16x8 b = *(const bf16x8*)(WP + (long)(((ntl * 8 + ks) << 6) + l) * 8);
#pragma unroll
            for (int ri = 0; ri < 2; ++ri)
                acc[j][ri] = __builtin_amdgcn_mfma_f32_16x16x32_bf16(
                    af[ri][ks], b, acc[j][ri], 0, 0, 0);
        }
    __builtin_amdgcn_s_setprio(0);

#pragma unroll
    for (int j = 0; j < 3; ++j) {
        int nt = w * 3 + j;
        __hip_bfloat16* OP = (nt < 4) ? Qb : ((nt < 8) ? Kb : Vb);
        const float* BP = (nt < 4) ? bq : ((nt < 8) ? bk : bv);
        int col = (nt & 3) * 16 + l15;
        float bias = BP[col];
#pragma unroll
        for (int ri = 0; ri < 2; ++ri)
#pragma unroll
            for (int rg = 0; rg < 4; ++rg) {
                long row = row0 + ri * 16 + lh * 4 + rg;
                OP[row * DD + col] = __float2bfloat16(acc[j][ri][rg] + bias);
            }
    }
}

// ---------------------------------------------------------------------------
// Gather-attention, bf16 K/V. One wave per token.
__global__ __launch_bounds__(256) void k_attn(const __hip_bfloat16* __restrict__ Q,
                                              const __hip_bfloat16* __restrict__ K,
                                              const __hip_bfloat16* __restrict__ V,
                                              const int* __restrict__ sel,
                                              __hip_bfloat16* __restrict__ ctx,
                                              float* __restrict__ attn_out) {
    const int wave  = threadIdx.x >> 6;
    const int lane  = threadIdx.x & 63;
    const int token = blockIdx.x * 4 + wave;
    const int b     = token >> 14;
    const float q   = __bfloat162float(Q[token * DD + lane]);

    int   idx[PP];
    float sc[PP];
    const int* selp = sel + (long)token * PP;
#pragma unroll
    for (int p = 0; p < PP; ++p) idx[p] = selp[p];

#pragma unroll
    for (int p = 0; p < PP; ++p) {
        float v = q * __bfloat162float(K[(((b << 14) + idx[p]) << 6) + lane]);
#pragma unroll
        for (int o = 32; o > 0; o >>= 1) v += __shfl_xor(v, o);
        sc[p] = v * 0.125f;
    }

    float mx = sc[0];
#pragma unroll
    for (int p = 1; p < PP; ++p) mx = fmaxf(mx, sc[p]);
    float e[PP];
    float s = 0.f;
#pragma unroll
    for (int p = 0; p < PP; ++p) { e[p] = expf(sc[p] - mx); s += e[p]; }
    const float inv = 1.f / s;

    float aval = 0.f;
#pragma unroll
    for (int p = 0; p < PP; ++p) aval = (lane == p) ? e[p] * inv : aval;
    if (lane < PP) attn_out[(long)token * PP + lane] = aval;

    float cv = 0.f;
#pragma unroll
    for (int p = 0; p < PP; ++p)
        cv += (e[p] * inv) * __bfloat162float(V[(((b << 14) + idx[p]) << 6) + lane]);
    ctx[token * DD + lane] = __float2bfloat16(cv);
}

// ---------------------------------------------------------------------------
// proj + LN1: Xn = LN(Xpb + ctx@Wo + bo)*g1 + be1 -> bf16.
// 32 rows/block, 4 waves. Wave w: row-tile ri=w&1, col-half nh=w>>1.
__global__ __launch_bounds__(256) void k_projln(
    const __hip_bfloat16* __restrict__ ctx, const __hip_bfloat16* __restrict__ WoP,
    const float* __restrict__ bo, const float* __restrict__ g1,
    const float* __restrict__ be1,
    const __hip_bfloat16* __restrict__ Xpb, __hip_bfloat16* __restrict__ Xnb) {
    __shared__ short Cs[32 * 64];       // 4 KB, swizzled
    __shared__ float red[2][32][2];
    __shared__ float mrs[32][2];
    const int t = threadIdx.x, w = t >> 6, l = t & 63;
    const int l15 = l & 15, lh = l >> 4;
    const int row0 = blockIdx.x * 32;

    {
        int r = t >> 3, ch = t & 7;                // 32 rows x 8 x 16B = 256
        int db = (r << 7) + (ch << 4);
        db ^= (r & 7) << 4;
        *(bf16x8*)((char*)Cs + db) = *(const bf16x8*)(ctx + (long)(row0 + r) * DD + ch * 8);
    }
    __syncthreads();

    const int ri = w & 1, nh = w >> 1;

    bf16x8 af[2];
#pragma unroll
    for (int ks = 0; ks < 2; ++ks) {
        int r = ri * 16 + l15;
        int db = (r << 7) + ks * 64 + lh * 16;
        db ^= (r & 7) << 4;
        af[ks] = *(const bf16x8*)((const char*)Cs + db);
    }

    f32x4 acc[8];
#pragma unroll
    for (int j = 0; j < 8; ++j) acc[j] = (f32x4)(0.f);

    __builtin_amdgcn_s_setprio(1);
#pragma unroll
    for (int ks = 0; ks < 2; ++ks)
#pragma unroll
        for (int j = 0; j < 8; ++j) {
            int nt = nh * 8 + j;
            bf16x8 b = *(const bf16x8*)(WoP + (long)(((nt * 2 + ks) << 6) + l) * 8);
            acc[j] = __builtin_amdgcn_mfma_f32_16x16x32_bf16(af[ks], b, acc[j], 0, 0, 0);
        }
    __builtin_amdgcn_s_setprio(0);

    float bov[8], g1v[8], be1v[8];
#pragma unroll
    for (int j = 0; j < 8; ++j) {
        int col = (nh * 8 + j) * 16 + l15;
        bov[j] = bo[col]; g1v[j] = g1[col]; be1v[j] = be1[col];
    }

    float xv[4][8];
#pragma unroll
    for (int rg = 0; rg < 4; ++rg) {
        long grow = row0 + ri * 16 + lh * 4 + rg;
        float s = 0.f, q = 0.f;
#pragma unroll
        for (int j = 0; j < 8; ++j) {
            float v = acc[j][rg] + bov[j] +
                      __bfloat162float(Xpb[grow * CC + (nh * 8 + j) * 16 + l15]);
            xv[rg][j] = v; s += v; q += v * v;
        }
#pragma unroll
        for (int o = 8; o > 0; o >>= 1) { s += __shfl_xor(s, o); q += __shfl_xor(q, o); }
        if (l15 == 0) {
            int rl = ri * 16 + lh * 4 + rg;
            red[nh][rl][0] = s; red[nh][rl][1] = q;
        }
    }
    __syncthreads();
    if (t < 32) {
        float S = red[0][t][0] + red[1][t][0];
        float Q = red[0][t][1] + red[1][t][1];
        float mu = S * (1.f / CC);
        float var = Q * (1.f / CC) - mu * mu;
        mrs[t][0] = mu; mrs[t][1] = rsqrtf(var + EPSF);
    }
    __syncthreads();
#pragma unroll
    for (int rg = 0; rg < 4; ++rg) {
        int rl = ri * 16 + lh * 4 + rg;
        long grow = row0 + rl;
        float mu = mrs[rl][0], rs = mrs[rl][1];
#pragma unroll
        for (int j = 0; j < 8; ++j)
            Xnb[grow * CC + (nh * 8 + j) * 16 + l15] =
                __float2bfloat16((xv[rg][j] - mu) * rs * g1v[j] + be1v[j]);
    }
}

// ---------------------------------------------------------------------------
// Fused FFN + LN2. 32 rows/block, 4 waves, 8 chunks of 128.
// Pipelined B-streams with RELAXED barriers (lgkm-only): global B-loads stay
// in flight across s_barrier; compiler emits counted vmcnt at use sites.
// Chunk order: issue b2r(c) -> phase1(b1r) -> issue b1r(c+1) -> H-write ->
//              BAR_LDS -> phase2(b2r).
__global__ __launch_bounds__(256) void k_ffn_mfma(
    const __hip_bfloat16* __restrict__ Xn,
    const __hip_bfloat16* __restrict__ W1P, const float* __restrict__ b1,
    const __hip_bfloat16* __restrict__ W2P, const float* __restrict__ b2,
    const float* __restrict__ g2, const float* __restrict__ be2,
    float* __restrict__ out) {
    __shared__ short Xs[32 * 256];      // 16 KB
    __shared__ short Hs[2][32 * 128];   // 16 KB
    __shared__ float red[4][32][2];     // 1 KB
    __shared__ float mrs[32][2];

    const int t = threadIdx.x, w = t >> 6, l = t & 63;
    const int l15 = l & 15, lh = l >> 4;
    const int row0 = blockIdx.x * 32;

    // ---- prologue: issue chunk-0 b1 fragments (latency hidden by staging) --
    bf16x8 b1r[2][8];
#pragma unroll
    for (int ci = 0; ci < 2; ++ci)
#pragma unroll
        for (int ks = 0; ks < 8; ++ks)
            b1r[ci][ks] = *(const bf16x8*)(
                W1P + (long)((((w * 2 + ci) * 8 + ks) << 6) + l) * 8);

    {
        const char* src = (const char*)(Xn + (long)row0 * CC);
        for (int j = t; j < 1024; j += 256) {      // 32 rows x 32 x 16B
            int r = j >> 5;
            int db = (r << 9) + ((j & 31) << 4);
            db ^= (r & 7) << 4;
            *(bf16x8*)((char*)Xs + db) = *(const bf16x8*)(src + ((long)j << 4));
        }
    }
    BAR_LDS();

    // hoist A fragments (chunk-invariant): [ri][ks]
    bf16x8 af[2][8];
#pragma unroll
    for (int ri = 0; ri < 2; ++ri)
#pragma unroll
        for (int ks = 0; ks < 8; ++ks) {
            int r = ri * 16 + l15;
            int db = (r << 9) + ks * 64 + lh * 16;
            db ^= (r & 7) << 4;
            af[ri][ks] = *(const bf16x8*)((const char*)Xs + db);
        }

    f32x4 oacc[2][4];
#pragma unroll
    for (int i = 0; i < 2; ++i)
#pragma unroll
        for (int j = 0; j < 4; ++j) oacc[i][j] = (f32x4)(0.f);

#pragma unroll 1
    for (int c = 0; c < 8; ++c) {
        // ---- issue this chunk's b2 fragments (covered by phase 1) ----
        bf16x8 b2r[4][4];
#pragma unroll
        for (int ci = 0; ci < 4; ++ci)
#pragma unroll
            for (int ks = 0; ks < 4; ++ks)
                b2r[ci][ks] = *(const bf16x8*)(
                    W2P + (long)((((w * 4 + ci) * 32 + c * 4 + ks) << 6) + l) * 8);

        // ---- phase 1: hacc = X @ W1c ----
        f32x4 hacc[2][2];
#pragma unroll
        for (int i = 0; i < 2; ++i)
#pragma unroll
            for (int j = 0; j < 2; ++j) hacc[i][j] = (f32x4)(0.f);

        __builtin_amdgcn_s_setprio(1);
#pragma unroll
        for (int ks = 0; ks < 8; ++ks)
#pragma unroll
            for (int ci = 0; ci < 2; ++ci)
#pragma unroll
                for (int ri = 0; ri < 2; ++ri)
                    hacc[ri][ci] = __builtin_amdgcn_mfma_f32_16x16x32_bf16(
                        af[ri][ks], b1r[ci][ks], hacc[ri][ci], 0, 0, 0);
        __builtin_amdgcn_s_setprio(0);

        // ---- issue next chunk's b1 fragments (in flight across barrier) ----
        if (c < 7) {
            int cn = c + 1;
#pragma unroll
            for (int ci = 0; ci < 2; ++ci)
#pragma unroll
                for (int ks = 0; ks < 8; ++ks)
                    b1r[ci][ks] = *(const bf16x8*)(
                        W1P + (long)((((cn * 8 + w * 2 + ci) * 8 + ks) << 6) + l) * 8);
        }

        // ---- write H = relu(hacc + b1) to LDS (bf16, swizzled) ----
        short* hb = Hs[c & 1];
#pragma unroll
        for (int ci = 0; ci < 2; ++ci) {
            float bias = b1[c * 128 + w * 32 + ci * 16 + l15];
            int colb = (w * 32 + ci * 16 + l15) * 2;
#pragma unroll
            for (int ri = 0; ri < 2; ++ri)
#pragma unroll
                for (int rg = 0; rg < 4; ++rg) {
                    int r = ri * 16 + lh * 4 + rg;
                    int db = (r << 8) + colb;
                    db ^= (r & 7) << 4;
                    *(__hip_bfloat16*)((char*)hb + db) =
                        __float2bfloat16(fmaxf(hacc[ri][ci][rg] + bias, 0.f));
                }
        }
        BAR_LDS();     // lgkm-only: b1r/b2r global loads stay in flight

        // ---- phase 2: oacc += H @ W2c ----
        __builtin_amdgcn_s_setprio(1);
#pragma unroll
        for (int ks = 0; ks < 4; ++ks) {
            bf16x8 a[2];
#pragma unroll
            for (int ri = 0; ri < 2; ++ri) {
                int r = ri * 16 + l15;
                int db = (r << 8) + ks * 64 + lh * 16;
                db ^= (r & 7) << 4;
                a[ri] = *(const bf16x8*)((const char*)hb + db);
            }
#pragma unroll
            for (int ci = 0; ci < 4; ++ci)
#pragma unroll
                for (int ri = 0; ri < 2; ++ri)
                    oacc[ri][ci] = __builtin_amdgcn_mfma_f32_16x16x32_bf16(
                        a[ri], b2r[ci][ks], oacc[ri][ci], 0, 0, 0);
        }
        __builtin_amdgcn_s_setprio(0);
        // Anti-dep note: Hs[c&1] is next overwritten in chunk c+2, after
        // BAR_LDS(c+1) has drained every wave's phase-2 reads of chunk c.
    }

    // ---- epilogue: residual + LN2 ----
    float b2c[4], g2c[4], be2c[4];
#pragma unroll
    for (int ci = 0; ci < 4; ++ci) {
        int n = w * 64 + ci * 16 + l15;
        b2c[ci] = b2[n]; g2c[ci] = g2[n]; be2c[ci] = be2[n];
    }
#pragma unroll
    for (int ri = 0; ri < 2; ++ri)
#pragma unroll
        for (int rg = 0; rg < 4; ++rg) {
            int r = ri * 16 + lh * 4 + rg;
            float s = 0.f, q = 0.f;
#pragma unroll
            for (int ci = 0; ci < 4; ++ci) {
                int db = (r << 9) + (w * 64 + ci * 16 + l15) * 2;
                db ^= (r & 7) << 4;
                float xn = __bfloat162float(*(__hip_bfloat16*)((char*)Xs + db));
                float v = oacc[ri][ci][rg] + xn + b2c[ci];
                oacc[ri][ci][rg] = v;
                s += v; q += v * v;
            }
#pragma unroll
            for (int o = 8; o > 0; o >>= 1) {
                s += __shfl_xor(s, o); q += __shfl_xor(q, o);
            }
            if (l15 == 0) { red[w][r][0] = s; red[w][r][1] = q; }
        }
    __syncthreads();
    if (t < 32) {
        float S = 0.f, Q = 0.f;
#pragma unroll
        for (int ww = 0; ww < 4; ++ww) { S += red[ww][t][0]; Q += red[ww][t][1]; }
        float mu = S * (1.f / CC);
        float var = Q * (1.f / CC) - mu * mu;
        mrs[t][0] = mu; mrs[t][1] = rsqrtf(var + EPSF);
    }
    __syncthreads();
#pragma unroll
    for (int ri = 0; ri < 2; ++ri)
#pragma unroll
        for (int rg = 0; rg < 4; ++rg) {
            int r = ri * 16 + lh * 4 + rg;
            float mu = mrs[r][0], rs = mrs[r][1];
#pragma unroll
            for (int ci = 0; ci < 4; ++ci) {
                int col = w * 64 + ci * 16 + l15;
                out[(long)(row0 + r) * CC + col] =
                    (oacc[ri][ci][rg] - mu) * rs * g2c[ci] + be2c[ci];
            }
        }
}

// ---------------------------------------------------------------------------
extern "C" void kernel_launch(void* const* d_in, const int* in_sizes, int n_in,
                              void* d_out, int out_size, void* d_ws, size_t ws_size,
                              hipStream_t stream) {
    const float* X   = (const float*)d_in[0];
    const int*   sel = (const int*)d_in[1];
    const float* pe  = (const float*)d_in[3];
    const float* Wq  = (const float*)d_in[4];
    const float* bq  = (const float*)d_in[5];
    const float* Wk  = (const float*)d_in[6];
    const float* bk  = (const float*)d_in[7];
    const float* Wv  = (const float*)d_in[8];
    const float* bv  = (const float*)d_in[9];
    const float* Wo  = (const float*)d_in[10];
    const float* bo  = (const float*)d_in[11];
    const float* W1  = (const float*)d_in[12];
    const float* b1  = (const float*)d_in[13];
    const float* W2  = (const float*)d_in[14];
    const float* b2  = (const float*)d_in[15];
    const float* g1  = (const float*)d_in[16];
    const float* be1 = (const float*)d_in[17];
    const float* g2  = (const float*)d_in[18];
    const float* be2 = (const float*)d_in[19];

    float* out = (float*)d_out;
    char*  ws  = (char*)d_ws;

    __hip_bfloat16* Xpb = (__hip_bfloat16*)(ws);                  // 16 MB
    __hip_bfloat16* Qb  = (__hip_bfloat16*)(ws + (16 << 20));     // 4 MB
    __hip_bfloat16* Kb  = (__hip_bfloat16*)(ws + (20 << 20));     // 4 MB
    __hip_bfloat16* Vb  = (__hip_bfloat16*)(ws + (24 << 20));     // 4 MB
    __hip_bfloat16* ctxb= (__hip_bfloat16*)(ws + (28 << 20));     // 4 MB
    __hip_bfloat16* Xnb = (__hip_bfloat16*)(ws + (32 << 20));     // 16 MB
    __hip_bfloat16* WqP = (__hip_bfloat16*)(ws + (48 << 20));     // 32 KB
    __hip_bfloat16* WkP = WqP + 16384;
    __hip_bfloat16* WvP = WkP + 16384;
    __hip_bfloat16* WoP = WvP + 16384;                            // 32 KB
    __hip_bfloat16* W1P = WoP + 16384;                            // 512 KB
    __hip_bfloat16* W2P = W1P + 262144;                           // 512 KB
    float* attn_out = out + (long)ROWS * CC;

    k_pack_all<<<2304, 256, 0, stream>>>(Wq, Wk, Wv, Wo, W1, W2,
                                         WqP, WkP, WvP, WoP, W1P, W2P);

    k_qkv<<<ROWS / 32, 256, 0, stream>>>((const float4*)X, (const float4*)pe,
                                         WqP, WkP, WvP, bq, bk, bv,
                                         Xpb, Qb, Kb, Vb);

    k_attn<<<ROWS / 4, 256, 0, stream>>>(Qb, Kb, Vb, sel, ctxb, attn_out);

    k_projln<<<ROWS / 32, 256, 0, stream>>>(ctxb, WoP, bo, g1, be1, Xpb, Xnb);

    k_ffn_mfma<<<ROWS / 32, 256, 0, stream>>>(Xnb, W1P, b1, W2P, b2, g2, be2, out);
}

// Round 8
// 157.173 us; speedup vs baseline: 1.0449x; 1.0449x over previous
//
#include <hip/hip_runtime.h>
#include <hip/hip_bf16.h>

#define CC 256
#define DD 64
#define PP 18
#define ROWS 32768
#define EPSF 1e-5f

typedef __attribute__((ext_vector_type(8))) short bf16x8;
typedef __attribute__((ext_vector_type(4))) short s16x4;
typedef __attribute__((ext_vector_type(4))) float f32x4;
typedef __attribute__((ext_vector_type(16))) float f32x16;

// Relaxed barrier: LDS handoff without draining vmcnt (keeps global B-frag
// loads in flight across the barrier).
#define BAR_LDS() do {                                        \
    asm volatile("s_waitcnt lgkmcnt(0)" ::: "memory");        \
    __builtin_amdgcn_s_barrier();                             \
    __builtin_amdgcn_sched_barrier(0);                        \
} while (0)

// ---------------------------------------------------------------------------
// Pack qkv + Wo weights into 16x16 MFMA B-fragment order (bf16):
// out[((nt*(K/32) + ks)*64 + l)*8 + e] = W[ks*32 + (l>>4)*8 + e][nt*16 + (l&15)]
__global__ __launch_bounds__(256) void k_pack_all(
    const float* __restrict__ Wq, const float* __restrict__ Wk,
    const float* __restrict__ Wv, const float* __restrict__ Wo,
    __hip_bfloat16* __restrict__ WqP, __hip_bfloat16* __restrict__ WkP,
    __hip_bfloat16* __restrict__ WvP, __hip_bfloat16* __restrict__ WoP) {
    int i = blockIdx.x * 256 + threadIdx.x;
    const float* src; __hip_bfloat16* dst; int K, N, j;
    if (i < 16384)       { src = Wq; dst = WqP; K = 256;  N = 64;   j = i; }
    else if (i < 32768)  { src = Wk; dst = WkP; K = 256;  N = 64;   j = i - 16384; }
    else if (i < 49152)  { src = Wv; dst = WvP; K = 256;  N = 64;   j = i - 32768; }
    else                 { src = Wo; dst = WoP; K = 64;   N = 256;  j = i - 49152; }
    int e = j & 7, l = (j >> 3) & 63, rest = j >> 9;
    int KS = K >> 5;
    int ks = rest % KS, nt = rest / KS;
    int row = ks * 32 + (l >> 4) * 8 + e;
    int col = nt * 16 + (l & 15);
    dst[j] = __float2bfloat16(src[(long)row * N + col]);
}

// ---------------------------------------------------------------------------
// Pack W1/W2 into 32x32x16 MFMA B-fragment order (bf16):
// out[((nt*(K/16) + ks)*64 + l)*8 + e] = W[ks*16 + (l>>5)*8 + e][nt*32 + (l&31)]
__global__ __launch_bounds__(256) void k_pack32(
    const float* __restrict__ W1, const float* __restrict__ W2,
    __hip_bfloat16* __restrict__ W1P, __hip_bfloat16* __restrict__ W2P) {
    int i = blockIdx.x * 256 + threadIdx.x;
    const float* src; __hip_bfloat16* dst; int K, N, j;
    if (i < 262144) { src = W1; dst = W1P; K = 256;  N = 1024; j = i; }
    else            { src = W2; dst = W2P; K = 1024; N = 256;  j = i - 262144; }
    int e = j & 7, l = (j >> 3) & 63, rest = j >> 9;
    int KS = K >> 4;
    int ks = rest % KS, nt = rest / KS;
    int row = ks * 16 + (l >> 5) * 8 + e;
    int col = nt * 32 + (l & 31);
    dst[j] = __float2bfloat16(src[(long)row * N + col]);
}

// ---------------------------------------------------------------------------
// Fused QKV (R4 version). 32 rows/block, 4 waves, 16x16 MFMA.
__global__ __launch_bounds__(256) void k_qkv(
    const float4* __restrict__ X4, const float4* __restrict__ pe4,
    const __hip_bfloat16* __restrict__ WqP, const __hip_bfloat16* __restrict__ WkP,
    const __hip_bfloat16* __restrict__ WvP,
    const float* __restrict__ bq, const float* __restrict__ bk,
    const float* __restrict__ bv,
    __hip_bfloat16* __restrict__ Xpb,
    __hip_bfloat16* __restrict__ Qb, __hip_bfloat16* __restrict__ Kb,
    __hip_bfloat16* __restrict__ Vb) {
    __shared__ short Xs[32 * 256];      // 16 KB, swizzled
    const int t = threadIdx.x, w = t >> 6, l = t & 63;
    const int l15 = l & 15, lh = l >> 4;
    const int row0 = blockIdx.x * 32;

    for (int j = t; j < 2048; j += 256) {          // 32 rows x 64 float4
        int r = j >> 6, c4 = j & 63;
        long g = row0 + r;
        float4 a = X4[(g << 6) + c4];
        float4 p = pe4[(long)((g & 16383) << 6) + c4];
        union { s16x4 v; __hip_bfloat16 h[4]; } u;
        u.h[0] = __float2bfloat16(a.x + p.x);
        u.h[1] = __float2bfloat16(a.y + p.y);
        u.h[2] = __float2bfloat16(a.z + p.z);
        u.h[3] = __float2bfloat16(a.w + p.w);
        int db = (r << 9) + (c4 << 3);
        db ^= (r & 7) << 4;
        *(s16x4*)((char*)Xs + db) = u.v;
        *(s16x4*)((char*)Xpb + (g << 9) + (c4 << 3)) = u.v;
    }
    __syncthreads();

    bf16x8 af[2][8];
#pragma unroll
    for (int ri = 0; ri < 2; ++ri)
#pragma unroll
        for (int ks = 0; ks < 8; ++ks) {
            int r = ri * 16 + l15;
            int db = (r << 9) + ks * 64 + lh * 16;
            db ^= (r & 7) << 4;
            af[ri][ks] = *(const bf16x8*)((const char*)Xs + db);
        }

    f32x4 acc[3][2];
#pragma unroll
    for (int j = 0; j < 3; ++j)
#pragma unroll
        for (int ri = 0; ri < 2; ++ri) acc[j][ri] = (f32x4)(0.f);

#pragma unroll
    for (int ks = 0; ks < 8; ++ks)
#pragma unroll
        for (int j = 0; j < 3; ++j) {
            int nt = w * 3 + j;
            const __hip_bfloat16* WP = (nt < 4) ? WqP : ((nt < 8) ? WkP : WvP);
            int ntl = nt & 3;
            bf16x8 b = *(const bf16x8*)(WP + (long)(((ntl * 8 + ks) << 6) + l) * 8);
#pragma unroll
            for (int ri = 0; ri < 2; ++ri)
                acc[j][ri] = __builtin_amdgcn_mfma_f32_16x16x32_bf16(
                    af[ri][ks], b, acc[j][ri], 0, 0, 0);
        }

#pragma unroll
    for (int j = 0; j < 3; ++j) {
        int nt = w * 3 + j;
        __hip_bfloat16* OP = (nt < 4) ? Qb : ((nt < 8) ? Kb : Vb);
        const float* BP = (nt < 4) ? bq : ((nt < 8) ? bk : bv);
        int col = (nt & 3) * 16 + l15;
        float bias = BP[col];
#pragma unroll
        for (int ri = 0; ri < 2; ++ri)
#pragma unroll
            for (int rg = 0; rg < 4; ++rg) {
                long row = row0 + ri * 16 + lh * 4 + rg;
                OP[row * DD + col] = __float2bfloat16(acc[j][ri][rg] + bias);
            }
    }
}

// ---------------------------------------------------------------------------
// Gather-attention, bf16 K/V. One wave per token.
__global__ __launch_bounds__(256) void k_attn(const __hip_bfloat16* __restrict__ Q,
                                              const __hip_bfloat16* __restrict__ K,
                                              const __hip_bfloat16* __restrict__ V,
                                              const int* __restrict__ sel,
                                              __hip_bfloat16* __restrict__ ctx,
                                              float* __restrict__ attn_out) {
    const int wave  = threadIdx.x >> 6;
    const int lane  = threadIdx.x & 63;
    const int token = blockIdx.x * 4 + wave;
    const int b     = token >> 14;
    const float q   = __bfloat162float(Q[token * DD + lane]);

    int   idx[PP];
    float sc[PP];
    const int* selp = sel + (long)token * PP;
#pragma unroll
    for (int p = 0; p < PP; ++p) idx[p] = selp[p];

#pragma unroll
    for (int p = 0; p < PP; ++p) {
        float v = q * __bfloat162float(K[(((b << 14) + idx[p]) << 6) + lane]);
#pragma unroll
        for (int o = 32; o > 0; o >>= 1) v += __shfl_xor(v, o);
        sc[p] = v * 0.125f;
    }

    float mx = sc[0];
#pragma unroll
    for (int p = 1; p < PP; ++p) mx = fmaxf(mx, sc[p]);
    float e[PP];
    float s = 0.f;
#pragma unroll
    for (int p = 0; p < PP; ++p) { e[p] = expf(sc[p] - mx); s += e[p]; }
    const float inv = 1.f / s;

    float aval = 0.f;
#pragma unroll
    for (int p = 0; p < PP; ++p) aval = (lane == p) ? e[p] * inv : aval;
    if (lane < PP) attn_out[(long)token * PP + lane] = aval;

    float cv = 0.f;
#pragma unroll
    for (int p = 0; p < PP; ++p)
        cv += (e[p] * inv) * __bfloat162float(V[(((b << 14) + idx[p]) << 6) + lane]);
    ctx[token * DD + lane] = __float2bfloat16(cv);
}

// ---------------------------------------------------------------------------
// proj + LN1 (R4 version). 32 rows/block, 4 waves, 16x16 MFMA.
__global__ __launch_bounds__(256) void k_projln(
    const __hip_bfloat16* __restrict__ ctx, const __hip_bfloat16* __restrict__ WoP,
    const float* __restrict__ bo, const float* __restrict__ g1,
    const float* __restrict__ be1,
    const __hip_bfloat16* __restrict__ Xpb, __hip_bfloat16* __restrict__ Xnb) {
    __shared__ short Cs[32 * 64];       // 4 KB, swizzled
    __shared__ float red[2][32][2];
    __shared__ float mrs[32][2];
    const int t = threadIdx.x, w = t >> 6, l = t & 63;
    const int l15 = l & 15, lh = l >> 4;
    const int row0 = blockIdx.x * 32;

    {
        int r = t >> 3, ch = t & 7;                // 32 rows x 8 x 16B = 256
        int db = (r << 7) + (ch << 4);
        db ^= (r & 7) << 4;
        *(bf16x8*)((char*)Cs + db) = *(const bf16x8*)(ctx + (long)(row0 + r) * DD + ch * 8);
    }
    __syncthreads();

    const int ri = w & 1, nh = w >> 1;

    bf16x8 af[2];
#pragma unroll
    for (int ks = 0; ks < 2; ++ks) {
        int r = ri * 16 + l15;
        int db = (r << 7) + ks * 64 + lh * 16;
        db ^= (r & 7) << 4;
        af[ks] = *(const bf16x8*)((const char*)Cs + db);
    }

    f32x4 acc[8];
#pragma unroll
    for (int j = 0; j < 8; ++j) acc[j] = (f32x4)(0.f);

#pragma unroll
    for (int ks = 0; ks < 2; ++ks)
#pragma unroll
        for (int j = 0; j < 8; ++j) {
            int nt = nh * 8 + j;
            bf16x8 b = *(const bf16x8*)(WoP + (long)(((nt * 2 + ks) << 6) + l) * 8);
            acc[j] = __builtin_amdgcn_mfma_f32_16x16x32_bf16(af[ks], b, acc[j], 0, 0, 0);
        }

    float bov[8], g1v[8], be1v[8];
#pragma unroll
    for (int j = 0; j < 8; ++j) {
        int col = (nh * 8 + j) * 16 + l15;
        bov[j] = bo[col]; g1v[j] = g1[col]; be1v[j] = be1[col];
    }

    float xv[4][8];
#pragma unroll
    for (int rg = 0; rg < 4; ++rg) {
        long grow = row0 + ri * 16 + lh * 4 + rg;
        float s = 0.f, q = 0.f;
#pragma unroll
        for (int j = 0; j < 8; ++j) {
            float v = acc[j][rg] + bov[j] +
                      __bfloat162float(Xpb[grow * CC + (nh * 8 + j) * 16 + l15]);
            xv[rg][j] = v; s += v; q += v * v;
        }
#pragma unroll
        for (int o = 8; o > 0; o >>= 1) { s += __shfl_xor(s, o); q += __shfl_xor(q, o); }
        if (l15 == 0) {
            int rl = ri * 16 + lh * 4 + rg;
            red[nh][rl][0] = s; red[nh][rl][1] = q;
        }
    }
    __syncthreads();
    if (t < 32) {
        float S = red[0][t][0] + red[1][t][0];
        float Q = red[0][t][1] + red[1][t][1];
        float mu = S * (1.f / CC);
        float var = Q * (1.f / CC) - mu * mu;
        mrs[t][0] = mu; mrs[t][1] = rsqrtf(var + EPSF);
    }
    __syncthreads();
#pragma unroll
    for (int rg = 0; rg < 4; ++rg) {
        int rl = ri * 16 + lh * 4 + rg;
        long grow = row0 + rl;
        float mu = mrs[rl][0], rs = mrs[rl][1];
#pragma unroll
        for (int j = 0; j < 8; ++j)
            Xnb[grow * CC + (nh * 8 + j) * 16 + l15] =
                __float2bfloat16((xv[rg][j] - mu) * rs * g1v[j] + be1v[j]);
    }
}

// ---------------------------------------------------------------------------
// Fused FFN + LN2, v3: 64 rows/block (512 blocks = 2/CU), 4 waves,
// 32x32x16 MFMA. Per 128-hidden chunk:
//   phase1: wave w computes H n-tile (c*4+w), rows 64 (2 ri), 16 k-steps.
//   phase2: wave w computes out cols w*64..+63 (2 n-tiles), 8 k-steps.
// B-frags batched per chunk from packed L2-resident layouts; relaxed
// barriers keep them in flight. 2x arithmetic intensity vs 32-row version.
__global__ __launch_bounds__(256) void k_ffn_mfma(
    const __hip_bfloat16* __restrict__ Xn,
    const __hip_bfloat16* __restrict__ W1P, const float* __restrict__ b1,
    const __hip_bfloat16* __restrict__ W2P, const float* __restrict__ b2,
    const float* __restrict__ g2, const float* __restrict__ be2,
    float* __restrict__ out) {
    __shared__ short Xs[64 * 256];      // 32 KB, row stride 512B, XOR swizzle
    __shared__ short Hs[2][64 * 128];   // 32 KB, row stride 256B, XOR swizzle
    __shared__ float red[4][64][2];     // 2 KB
    __shared__ float mrs[64][2];

    const int t = threadIdx.x, w = t >> 6, l = t & 63;
    const int l31 = l & 31, lk = l >> 5;
    const int row0 = blockIdx.x * 64;

    // ---- prologue: issue chunk-0 b1 fragments (covered by staging) ----
    bf16x8 b1r[16];
#pragma unroll
    for (int ks = 0; ks < 16; ++ks)
        b1r[ks] = *(const bf16x8*)(W1P + (long)(((w * 16 + ks) << 6) + l) * 8);

    {
        const char* src = (const char*)(Xn + (long)row0 * CC);
        for (int j = t; j < 2048; j += 256) {      // 64 rows x 32 x 16B
            int r = j >> 5;
            int db = (r << 9) + ((j & 31) << 4);
            db ^= (r & 7) << 4;
            *(bf16x8*)((char*)Xs + db) = *(const bf16x8*)(src + ((long)j << 4));
        }
    }
    BAR_LDS();

    f32x16 oacc[2][2];                  // [ri][nt2]
#pragma unroll
    for (int i = 0; i < 2; ++i)
#pragma unroll
        for (int j = 0; j < 2; ++j) oacc[i][j] = (f32x16)(0.f);

    const int swz0 = (l31 & 7) << 4;    // same for row l31 and row 32+l31

#pragma unroll 1
    for (int c = 0; c < 8; ++c) {
        // ---- issue this chunk's b2 fragments (covered by phase 1) ----
        bf16x8 b2r[2][8];
#pragma unroll
        for (int nt2 = 0; nt2 < 2; ++nt2)
#pragma unroll
            for (int ks = 0; ks < 8; ++ks)
                b2r[nt2][ks] = *(const bf16x8*)(
                    W2P + (long)(((((w * 2 + nt2) * 64) + c * 8 + ks) << 6) + l) * 8);
        float b1v = b1[c * 128 + w * 32 + l31];

        // ---- phase 1: H n-tile (c*4+w) = X @ W1 ----
        f32x16 hacc[2];
        hacc[0] = (f32x16)(0.f);
        hacc[1] = (f32x16)(0.f);

        __builtin_amdgcn_s_setprio(1);
#pragma unroll
        for (int ks = 0; ks < 16; ++ks) {
            int db0 = (l31 << 9) + ks * 32 + lk * 16;
            bf16x8 a0 = *(const bf16x8*)((const char*)Xs + (db0 ^ swz0));
            int db1 = ((32 + l31) << 9) + ks * 32 + lk * 16;
            bf16x8 a1 = *(const bf16x8*)((const char*)Xs + (db1 ^ swz0));
            hacc[0] = __builtin_amdgcn_mfma_f32_32x32x16_bf16(a0, b1r[ks], hacc[0], 0, 0, 0);
            hacc[1] = __builtin_amdgcn_mfma_f32_32x32x16_bf16(a1, b1r[ks], hacc[1], 0, 0, 0);
        }
        __builtin_amdgcn_s_setprio(0);

        // ---- issue next chunk's b1 fragments (in flight across barrier) ----
        if (c < 7) {
            int ntg = (c + 1) * 4 + w;
#pragma unroll
            for (int ks = 0; ks < 16; ++ks)
                b1r[ks] = *(const bf16x8*)(
                    W1P + (long)(((ntg * 16 + ks) << 6) + l) * 8);
        }

        // ---- write H = relu(hacc + b1) to LDS ----
        short* hb = Hs[c & 1];
        {
            int colb = (w * 32 + l31) << 1;
#pragma unroll
            for (int ri = 0; ri < 2; ++ri)
#pragma unroll
                for (int reg = 0; reg < 16; ++reg) {
                    int row = ri * 32 + (reg & 3) + ((reg >> 2) << 3) + (lk << 2);
                    int db = (row << 8) + colb;
                    db ^= (row & 7) << 4;
                    *(__hip_bfloat16*)((char*)hb + db) =
                        __float2bfloat16(fmaxf(hacc[ri][reg] + b1v, 0.f));
                }
        }
        BAR_LDS();

        // ---- phase 2: oacc += H @ W2 ----
        __builtin_amdgcn_s_setprio(1);
#pragma unroll
        for (int ks = 0; ks < 8; ++ks) {
            int db0 = (l31 << 8) + ks * 32 + lk * 16;
            bf16x8 a0 = *(const bf16x8*)((const char*)hb + (db0 ^ swz0));
            int db1 = ((32 + l31) << 8) + ks * 32 + lk * 16;
            bf16x8 a1 = *(const bf16x8*)((const char*)hb + (db1 ^ swz0));
#pragma unroll
            for (int nt2 = 0; nt2 < 2; ++nt2) {
                oacc[0][nt2] = __builtin_amdgcn_mfma_f32_32x32x16_bf16(
                    a0, b2r[nt2][ks], oacc[0][nt2], 0, 0, 0);
                oacc[1][nt2] = __builtin_amdgcn_mfma_f32_32x32x16_bf16(
                    a1, b2r[nt2][ks], oacc[1][nt2], 0, 0, 0);
            }
        }
        __builtin_amdgcn_s_setprio(0);
        // Hs[c&1] next overwritten in chunk c+2, after BAR_LDS(c+1) ensures
        // all waves finished phase-2 reads of chunk c.
    }

    // ---- epilogue: residual + LN2 ----
    float b2v[2], g2v[2], be2v[2];
#pragma unroll
    for (int nt2 = 0; nt2 < 2; ++nt2) {
        int col = w * 64 + nt2 * 32 + l31;
        b2v[nt2] = b2[col]; g2v[nt2] = g2[col]; be2v[nt2] = be2[col];
    }
#pragma unroll
    for (int ri = 0; ri < 2; ++ri)
#pragma unroll
        for (int reg = 0; reg < 16; ++reg) {
            int rloc = ri * 32 + (reg & 3) + ((reg >> 2) << 3) + (lk << 2);
            float s = 0.f, q = 0.f;
#pragma unroll
            for (int nt2 = 0; nt2 < 2; ++nt2) {
                int col = w * 64 + nt2 * 32 + l31;
                int db = (rloc << 9) + (col << 1);
                db ^= (rloc & 7) << 4;
                float xn = __bfloat162float(*(__hip_bfloat16*)((char*)Xs + db));
                float v = oacc[ri][nt2][reg] + xn + b2v[nt2];
                oacc[ri][nt2][reg] = v;
                s += v; q += v * v;
            }
#pragma unroll
            for (int o = 16; o > 0; o >>= 1) {     // reduce within 32-lane half
                s += __shfl_xor(s, o); q += __shfl_xor(q, o);
            }
            if (l31 == 0) { red[w][rloc][0] = s; red[w][rloc][1] = q; }
        }
    __syncthreads();
    if (t < 64) {
        float S = 0.f, Q = 0.f;
#pragma unroll
        for (int ww = 0; ww < 4; ++ww) { S += red[ww][t][0]; Q += red[ww][t][1]; }
        float mu = S * (1.f / CC);
        float var = Q * (1.f / CC) - mu * mu;
        mrs[t][0] = mu; mrs[t][1] = rsqrtf(var + EPSF);
    }
    __syncthreads();
#pragma unroll
    for (int ri = 0; ri < 2; ++ri)
#pragma unroll
        for (int reg = 0; reg < 16; ++reg) {
            int rloc = ri * 32 + (reg & 3) + ((reg >> 2) << 3) + (lk << 2);
            float mu = mrs[rloc][0], rs = mrs[rloc][1];
#pragma unroll
            for (int nt2 = 0; nt2 < 2; ++nt2) {
                int col = w * 64 + nt2 * 32 + l31;
                out[(long)(row0 + rloc) * CC + col] =
                    (oacc[ri][nt2][reg] - mu) * rs * g2v[nt2] + be2v[nt2];
            }
        }
}

// ---------------------------------------------------------------------------
extern "C" void kernel_launch(void* const* d_in, const int* in_sizes, int n_in,
                              void* d_out, int out_size, void* d_ws, size_t ws_size,
                              hipStream_t stream) {
    const float* X   = (const float*)d_in[0];
    const int*   sel = (const int*)d_in[1];
    const float* pe  = (const float*)d_in[3];
    const float* Wq  = (const float*)d_in[4];
    const float* bq  = (const float*)d_in[5];
    const float* Wk  = (const float*)d_in[6];
    const float* bk  = (const float*)d_in[7];
    const float* Wv  = (const float*)d_in[8];
    const float* bv  = (const float*)d_in[9];
    const float* Wo  = (const float*)d_in[10];
    const float* bo  = (const float*)d_in[11];
    const float* W1  = (const float*)d_in[12];
    const float* b1  = (const float*)d_in[13];
    const float* W2  = (const float*)d_in[14];
    const float* b2  = (const float*)d_in[15];
    const float* g1  = (const float*)d_in[16];
    const float* be1 = (const float*)d_in[17];
    const float* g2  = (const float*)d_in[18];
    const float* be2 = (const float*)d_in[19];

    float* out = (float*)d_out;
    char*  ws  = (char*)d_ws;

    __hip_bfloat16* Xpb = (__hip_bfloat16*)(ws);                  // 16 MB
    __hip_bfloat16* Qb  = (__hip_bfloat16*)(ws + (16 << 20));     // 4 MB
    __hip_bfloat16* Kb  = (__hip_bfloat16*)(ws + (20 << 20));     // 4 MB
    __hip_bfloat16* Vb  = (__hip_bfloat16*)(ws + (24 << 20));     // 4 MB
    __hip_bfloat16* ctxb= (__hip_bfloat16*)(ws + (28 << 20));     // 4 MB
    __hip_bfloat16* Xnb = (__hip_bfloat16*)(ws + (32 << 20));     // 16 MB
    __hip_bfloat16* WqP = (__hip_bfloat16*)(ws + (48 << 20));     // 32 KB
    __hip_bfloat16* WkP = WqP + 16384;
    __hip_bfloat16* WvP = WkP + 16384;
    __hip_bfloat16* WoP = WvP + 16384;                            // 32 KB
    __hip_bfloat16* W1P = WoP + 16384;                            // 512 KB (32x32 layout)
    __hip_bfloat16* W2P = W1P + 262144;                           // 512 KB (32x32 layout)
    float* attn_out = out + (long)ROWS * CC;

    k_pack_all<<<256, 256, 0, stream>>>(Wq, Wk, Wv, Wo, WqP, WkP, WvP, WoP);
    k_pack32<<<2048, 256, 0, stream>>>(W1, W2, W1P, W2P);

    k_qkv<<<ROWS / 32, 256, 0, stream>>>((const float4*)X, (const float4*)pe,
                                         WqP, WkP, WvP, bq, bk, bv,
                                         Xpb, Qb, Kb, Vb);

    k_attn<<<ROWS / 4, 256, 0, stream>>>(Qb, Kb, Vb, sel, ctxb, attn_out);

    k_projln<<<ROWS / 32, 256, 0, stream>>>(ctxb, WoP, bo, g1, be1, Xpb, Xnb);

    k_ffn_mfma<<<ROWS / 64, 256, 0, stream>>>(Xnb, W1P, b1, W2P, b2, g2, be2, out);
}